// Round 1
// baseline (2297.155 us; speedup 1.0000x reference)
//
#include <hip/hip_runtime.h>

#define HID 256
#define TT  2048
#define NB  128

// Persistent RNN: one block per batch row, whole T-loop in-kernel.
// thread (i = tid>>2, c = tid&3): owns W_hh[i][64c .. 64c+64) in registers.
__global__ __launch_bounds__(1024, 1) void rnn_persist(
    const float* __restrict__ x,      // [B, T, 1]
    const float* __restrict__ W_ih,   // [256, 1]
    const float* __restrict__ W_hh,   // [256, 256]
    const float* __restrict__ b_ih,   // [256]
    const float* __restrict__ b_hh,   // [256]
    const float* __restrict__ W_out,  // [1, 256]
    const float* __restrict__ b_out,  // [1]
    float* __restrict__ y)            // [B, T, 1]
{
    // h stored as 4 chunks of 64 floats, each chunk padded to 68 words so the
    // 4 per-instruction ds_read_b128 addresses (one per c) hit disjoint banks:
    // word = 68c + 4g -> banks {4g+4c .. 4g+4c+3} mod 32, 16 distinct banks.
    __shared__ __align__(16) float s_h[2][4 * 68];
    __shared__ float s_x[TT];
    __shared__ float s_yp[2][16];

    const int tid = threadIdx.x;
    const int i   = tid >> 2;
    const int c   = tid & 3;
    const int b   = blockIdx.x;

    // stage x row (coalesced, broadcast-read later)
    for (int k = tid; k < TT; k += 1024) s_x[k] = x[(size_t)b * TT + k];

    // weights resident in registers (static indexing only)
    float4 w[16];
    const float* wrow = W_hh + i * HID + c * 64;
    #pragma unroll
    for (int g = 0; g < 16; ++g)
        w[g] = *(const float4*)(wrow + 4 * g);

    const float wih  = W_ih[i];
    const float bias = b_ih[i] + b_hh[i];
    const float wout = W_out[i];
    const float bout = b_out[0];

    // h0 = 0 (zero pads too)
    if (tid < 4 * 68) { s_h[0][tid] = 0.0f; s_h[1][tid] = 0.0f; }
    __syncthreads();

    int p = 0;
    float* yrow = y + (size_t)b * TT;

    for (int step = 0; step < TT; ++step) {
        const float xt = s_x[step];
        const float* hbase = &s_h[p][c * 68];

        float d0 = 0.0f, d1 = 0.0f;
        #pragma unroll
        for (int g = 0; g < 16; g += 2) {
            const float4 ha = *(const float4*)(hbase + 4 * g);
            const float4 hb = *(const float4*)(hbase + 4 * (g + 1));
            d0 = fmaf(ha.x, w[g].x, d0);
            d0 = fmaf(ha.y, w[g].y, d0);
            d0 = fmaf(ha.z, w[g].z, d0);
            d0 = fmaf(ha.w, w[g].w, d0);
            d1 = fmaf(hb.x, w[g + 1].x, d1);
            d1 = fmaf(hb.y, w[g + 1].y, d1);
            d1 = fmaf(hb.z, w[g + 1].z, d1);
            d1 = fmaf(hb.w, w[g + 1].w, d1);
        }
        float dot = d0 + d1;
        // reduce across the 4 chunks (lanes tid^1, tid^2 are same wave)
        dot += __shfl_xor(dot, 1);
        dot += __shfl_xor(dot, 2);

        const float hn = tanhf(fmaf(xt, wih, bias) + dot);

        // write h_new into the other buffer (chunked+padded layout)
        if (c == 0) s_h[p ^ 1][(i >> 6) * 68 + (i & 63)] = hn;

        // fused output projection: y_t = sum_i hn[i]*wout[i] + bout
        float yp = (c == 0) ? hn * wout : 0.0f;
        yp += __shfl_xor(yp, 4);
        yp += __shfl_xor(yp, 8);
        yp += __shfl_xor(yp, 16);
        yp += __shfl_xor(yp, 32);
        if ((tid & 63) == 0) s_yp[step & 1][tid >> 6] = yp;

        __syncthreads();

        if (tid < 16) {
            float v = s_yp[step & 1][tid];
            v += __shfl_xor(v, 1);
            v += __shfl_xor(v, 2);
            v += __shfl_xor(v, 4);
            v += __shfl_xor(v, 8);
            if (tid == 0) yrow[step] = v + bout;
        }
        p ^= 1;
    }
}

extern "C" void kernel_launch(void* const* d_in, const int* in_sizes, int n_in,
                              void* d_out, int out_size, void* d_ws, size_t ws_size,
                              hipStream_t stream) {
    const float* x     = (const float*)d_in[0];
    const float* W_ih  = (const float*)d_in[1];
    const float* W_hh  = (const float*)d_in[2];
    const float* b_ih  = (const float*)d_in[3];
    const float* b_hh  = (const float*)d_in[4];
    const float* W_out = (const float*)d_in[5];
    const float* b_out = (const float*)d_in[6];
    float* y = (float*)d_out;

    hipLaunchKernelGGL(rnn_persist, dim3(NB), dim3(1024), 0, stream,
                       x, W_ih, W_hh, b_ih, b_hh, W_out, b_out, y);
}

// Round 3
// 1644.704 us; speedup vs baseline: 1.3967x; 1.3967x over previous
//
#include <hip/hip_runtime.h>

#define HID  256
#define TT   2048
#define NB   128
#define NTHR 512

// DPP-based add of a rotated copy (VALU pipe, no LDS traffic).
// 0xB1 = quad_perm xor1, 0x4E = quad_perm xor2, 0x124 = row_ror:4, 0x128 = row_ror:8
template <int CTRL>
__device__ __forceinline__ float dpp_add(float v) {
    int t = __builtin_amdgcn_update_dpp(0, __float_as_int(v), CTRL, 0xF, 0xF, true);
    return v + __int_as_float(t);
}

__device__ __forceinline__ float tanh_fast(float x) {
    // tanh(x) = 1 - 2/(e^{2x}+1); exp inf/0 limits give +-1 correctly.
    float e = __expf(2.0f * x);
    float r = __builtin_amdgcn_rcpf(e + 1.0f);
    return fmaf(-2.0f, r, 1.0f);
}

// Persistent RNN: one block per batch row. thread (rg = tid>>4, c3 = tid&15)
// owns rows 8*rg..8*rg+7, cols 16*c3..16*c3+15 of W_hh in registers (128 VGPR).
// LDS h traffic: 512 thr * 64 B = 32 KB/step (vs 256 KB in v1).
__global__ __launch_bounds__(NTHR, 2) void rnn_persist(
    const float* __restrict__ x,      // [B, T, 1]
    const float* __restrict__ W_ih,   // [256, 1]
    const float* __restrict__ W_hh,   // [256, 256]
    const float* __restrict__ b_ih,   // [256]
    const float* __restrict__ b_hh,   // [256]
    const float* __restrict__ W_out,  // [1, 256]
    const float* __restrict__ b_out,  // [1]
    float* __restrict__ y)            // [B, T, 1]
{
    // h stored as 8 chunks of 32 floats, each chunk padded to 36 words:
    // word(i) = 36*(i>>5) + (i&31). Read addrs 36*(c3>>1)+16*(c3&1)+4g are
    // at worst 2-way bank-aliased (free per m136).
    __shared__ __align__(16) float s_h[2][8 * 36];
    __shared__ float s_x[TT];

    const int tid  = threadIdx.x;
    const int c3   = tid & 15;   // col chunk (16 cols)
    const int rg   = tid >> 4;   // row group (8 rows), 0..31
    const int lane = tid & 63;
    const int wv   = tid >> 6;   // wave 0..7
    const int b    = blockIdx.x;

    // stage x row
    for (int k = tid; k < TT; k += NTHR) s_x[k] = x[(size_t)b * TT + k];

    // weights resident in registers (all indices compile-time after unroll)
    float4 w[8][4];
    #pragma unroll
    for (int r = 0; r < 8; ++r)
        #pragma unroll
        for (int g = 0; g < 4; ++g)
            w[r][g] = *(const float4*)&W_hh[(8 * rg + r) * HID + 16 * c3 + 4 * g];

    const int   myrow = 8 * rg + (c3 & 7);          // row this lane finalizes (c3<8)
    const float wih   = W_ih[myrow];
    const float bias  = b_ih[myrow] + b_hh[myrow];
    const float4 wo   = *(const float4*)&W_out[4 * lane];  // for y-duty
    const float bout  = b_out[0];

    // h0 = 0
    if (tid < 256) {
        int wd = 36 * (tid >> 5) + (tid & 31);
        s_h[0][wd] = 0.0f;
        s_h[1][wd] = 0.0f;
    }
    __syncthreads();

    int p = 0;
    float* yrow = y + (size_t)b * TT;
    const int hwword = 36 * (myrow >> 5) + (myrow & 31);        // h write addr
    const int rdbase = 36 * (c3 >> 1) + 16 * (c3 & 1);          // h read base
    const int ybase  = 36 * (lane >> 3) + ((4 * lane) & 31);    // y-duty read

    for (int step = 0; step <= TT; ++step) {
        // ---- output y_{step-1} (rotating duty wave; overlaps this step) ----
        if (step >= 1 && wv == ((step - 1) & 7)) {
            float4 hv = *(const float4*)&s_h[p][ybase];   // full h, 4 vals/lane
            float pv = hv.x * wo.x + hv.y * wo.y + hv.z * wo.z + hv.w * wo.w;
            pv += __shfl_xor(pv, 1);
            pv += __shfl_xor(pv, 2);
            pv += __shfl_xor(pv, 4);
            pv += __shfl_xor(pv, 8);
            pv += __shfl_xor(pv, 16);
            pv += __shfl_xor(pv, 32);
            if (lane == 0) yrow[step - 1] = pv + bout;
        }
        if (step == TT) break;

        const float xt = s_x[step];
        const float* hb = &s_h[p][rdbase];
        const float4 h0 = *(const float4*)(hb);
        const float4 h1 = *(const float4*)(hb + 4);
        const float4 h2 = *(const float4*)(hb + 8);
        const float4 h3 = *(const float4*)(hb + 12);

        float acc[8];
        #pragma unroll
        for (int r = 0; r < 8; ++r) acc[r] = 0.0f;
        #pragma unroll
        for (int r = 0; r < 8; ++r) {
            acc[r] = fmaf(h0.x, w[r][0].x, acc[r]);
            acc[r] = fmaf(h0.y, w[r][0].y, acc[r]);
            acc[r] = fmaf(h0.z, w[r][0].z, acc[r]);
            acc[r] = fmaf(h0.w, w[r][0].w, acc[r]);
            acc[r] = fmaf(h1.x, w[r][1].x, acc[r]);
            acc[r] = fmaf(h1.y, w[r][1].y, acc[r]);
            acc[r] = fmaf(h1.z, w[r][1].z, acc[r]);
            acc[r] = fmaf(h1.w, w[r][1].w, acc[r]);
            acc[r] = fmaf(h2.x, w[r][2].x, acc[r]);
            acc[r] = fmaf(h2.y, w[r][2].y, acc[r]);
            acc[r] = fmaf(h2.z, w[r][2].z, acc[r]);
            acc[r] = fmaf(h2.w, w[r][2].w, acc[r]);
            acc[r] = fmaf(h3.x, w[r][3].x, acc[r]);
            acc[r] = fmaf(h3.y, w[r][3].y, acc[r]);
            acc[r] = fmaf(h3.z, w[r][3].z, acc[r]);
            acc[r] = fmaf(h3.w, w[r][3].w, acc[r]);
        }

        // reduce across the 16 col-chunk lanes (bits 0..3 of tid), pure DPP
        #pragma unroll
        for (int r = 0; r < 8; ++r) {
            acc[r] = dpp_add<0xB1>(acc[r]);   // xor1
            acc[r] = dpp_add<0x4E>(acc[r]);   // xor2
            acc[r] = dpp_add<0x124>(acc[r]);  // ror4 (rotation sums OK for +)
            acc[r] = dpp_add<0x128>(acc[r]);  // ror8 -> all 16 lanes have totals
        }

        if ((c3 & 8) == 0) {
            // lane c3 (0..7) finalizes row 8*rg + c3: static binary select
            float s01 = (c3 & 1) ? acc[1] : acc[0];
            float s23 = (c3 & 1) ? acc[3] : acc[2];
            float s45 = (c3 & 1) ? acc[5] : acc[4];
            float s67 = (c3 & 1) ? acc[7] : acc[6];
            float sA  = (c3 & 2) ? s23 : s01;
            float sB  = (c3 & 2) ? s67 : s45;
            float dot = (c3 & 4) ? sB : sA;
            float hn = tanh_fast(fmaf(xt, wih, bias) + dot);
            s_h[p ^ 1][hwword] = hn;
        }
        __syncthreads();
        p ^= 1;
    }
}

extern "C" void kernel_launch(void* const* d_in, const int* in_sizes, int n_in,
                              void* d_out, int out_size, void* d_ws, size_t ws_size,
                              hipStream_t stream) {
    const float* x     = (const float*)d_in[0];
    const float* W_ih  = (const float*)d_in[1];
    const float* W_hh  = (const float*)d_in[2];
    const float* b_ih  = (const float*)d_in[3];
    const float* b_hh  = (const float*)d_in[4];
    const float* W_out = (const float*)d_in[5];
    const float* b_out = (const float*)d_in[6];
    float* y = (float*)d_out;

    hipLaunchKernelGGL(rnn_persist, dim3(NB), dim3(NTHR), 0, stream,
                       x, W_ih, W_hh, b_ih, b_hh, W_out, b_out, y);
}

// Round 5
// 1497.803 us; speedup vs baseline: 1.5337x; 1.0981x over previous
//
#include <hip/hip_runtime.h>

#define HID  256
#define TT   2048
#define NB   128
#define NTHR 512

// DPP-based add of a rotated copy (VALU pipe, no LDS traffic).
// 0xB1 = quad_perm xor1, 0x4E = quad_perm xor2, 0x124 = row_ror:4, 0x128 = row_ror:8
template <int CTRL>
__device__ __forceinline__ float dpp_add(float v) {
    int t = __builtin_amdgcn_update_dpp(0, __float_as_int(v), CTRL, 0xF, 0xF, true);
    return v + __int_as_float(t);
}

__device__ __forceinline__ float tanh_fast(float x) {
    // tanh(x) = 1 - 2/(e^{2x}+1); exp inf/0 limits give +-1 correctly.
    float e = __expf(2.0f * x);
    float r = __builtin_amdgcn_rcpf(e + 1.0f);
    return fmaf(-2.0f, r, 1.0f);
}

// Persistent RNN: one block per batch row. thread (rg = tid>>4, c3 = tid&15)
// owns rows 8*rg..8*rg+7, cols 16*c3..16*c3+15 of W_hh in registers.
// Weights are loaded VOLATILE: LLVM cannot rematerialize/re-execute volatile
// accesses, so the 128 floats must stay VGPR-resident. (Round 2's VGPR=88
// proved the plain loads were re-fetched from L2 every step: 67 GB total
// = 39 TB/s = the real bottleneck. Round 3's "+v" float4 pin didn't compile:
// tied indirect register inputs.)
__global__ __launch_bounds__(NTHR, 2) void rnn_persist(
    const float* __restrict__ x,      // [B, T, 1]
    const float* __restrict__ W_ih,   // [256, 1]
    const float* __restrict__ W_hh,   // [256, 256]
    const float* __restrict__ b_ih,   // [256]
    const float* __restrict__ b_hh,   // [256]
    const float* __restrict__ W_out,  // [1, 256]
    const float* __restrict__ b_out,  // [1]
    float* __restrict__ y)            // [B, T, 1]
{
    // h stored as 8 chunks of 32 floats, each chunk padded to 36 words:
    // 16 distinct read addrs, 2 per 4-bank group (2-way aliasing is ~free
    // per m136); same-c3 lanes broadcast.
    __shared__ __align__(16) float s_h[2][8 * 36];
    __shared__ float s_x[TT];
    __shared__ float s_part[2][8];

    const int tid  = threadIdx.x;
    const int c3   = tid & 15;   // col chunk (16 cols)
    const int rg   = tid >> 4;   // row group (8 rows), 0..31
    const int lane = tid & 63;
    const int wv   = tid >> 6;   // wave 0..7
    const int b    = blockIdx.x;

    // stage x row
    for (int k = tid; k < TT; k += NTHR) s_x[k] = x[(size_t)b * TT + k];

    // weights resident in registers — volatile loads are remat-proof
    float4 w[8][4];
    #pragma unroll
    for (int r = 0; r < 8; ++r) {
        const volatile float* wp = &W_hh[(8 * rg + r) * HID + 16 * c3];
        #pragma unroll
        for (int g = 0; g < 4; ++g) {
            w[r][g].x = wp[4 * g + 0];
            w[r][g].y = wp[4 * g + 1];
            w[r][g].z = wp[4 * g + 2];
            w[r][g].w = wp[4 * g + 3];
        }
    }

    const int   myrow = 8 * rg + (c3 & 7);   // row this lane finalizes
    const float wih   = W_ih[myrow];
    const float bias  = b_ih[myrow] + b_hh[myrow];
    const float wo_my = W_out[myrow];
    const float bout  = b_out[0];

    // h0 = 0
    if (tid < 256) {
        int wd = 36 * (tid >> 5) + (tid & 31);
        s_h[0][wd] = 0.0f;
        s_h[1][wd] = 0.0f;
    }
    __syncthreads();

    int p = 0;
    float* yrow = y + (size_t)b * TT;
    const int hwword = 36 * (myrow >> 5) + (myrow & 31);   // h write addr
    const int rdbase = 36 * (c3 >> 1) + 16 * (c3 & 1);     // h read base

    for (int step = 0; step <= TT; ++step) {
        // ---- finalize y_{step-1}: rotating wave sums the 8 per-wave partials
        if (step >= 1 && wv == ((step - 1) & 7)) {
            float pp = s_part[(step - 1) & 1][lane & 7];   // broadcast-pattern read
            pp = dpp_add<0xB1>(pp);
            pp = dpp_add<0x4E>(pp);
            pp = dpp_add<0x124>(pp);
            if (lane == 0) yrow[step - 1] = pp + bout;
        }
        if (step == TT) break;

        const float xt = s_x[step];
        const float* hb = &s_h[p][rdbase];
        const float4 h0 = *(const float4*)(hb);
        const float4 h1 = *(const float4*)(hb + 4);
        const float4 h2 = *(const float4*)(hb + 8);
        const float4 h3 = *(const float4*)(hb + 12);

        float acc[8];
        #pragma unroll
        for (int r = 0; r < 8; ++r) acc[r] = 0.0f;
        #pragma unroll
        for (int r = 0; r < 8; ++r) {
            acc[r] = fmaf(h0.x, w[r][0].x, acc[r]);
            acc[r] = fmaf(h0.y, w[r][0].y, acc[r]);
            acc[r] = fmaf(h0.z, w[r][0].z, acc[r]);
            acc[r] = fmaf(h0.w, w[r][0].w, acc[r]);
            acc[r] = fmaf(h1.x, w[r][1].x, acc[r]);
            acc[r] = fmaf(h1.y, w[r][1].y, acc[r]);
            acc[r] = fmaf(h1.z, w[r][1].z, acc[r]);
            acc[r] = fmaf(h1.w, w[r][1].w, acc[r]);
            acc[r] = fmaf(h2.x, w[r][2].x, acc[r]);
            acc[r] = fmaf(h2.y, w[r][2].y, acc[r]);
            acc[r] = fmaf(h2.z, w[r][2].z, acc[r]);
            acc[r] = fmaf(h2.w, w[r][2].w, acc[r]);
            acc[r] = fmaf(h3.x, w[r][3].x, acc[r]);
            acc[r] = fmaf(h3.y, w[r][3].y, acc[r]);
            acc[r] = fmaf(h3.z, w[r][3].z, acc[r]);
            acc[r] = fmaf(h3.w, w[r][3].w, acc[r]);
        }

        // reduce across the 16 col-chunk lanes (bits 0..3 of tid), pure DPP
        #pragma unroll
        for (int r = 0; r < 8; ++r) {
            acc[r] = dpp_add<0xB1>(acc[r]);   // xor1
            acc[r] = dpp_add<0x4E>(acc[r]);   // xor2
            acc[r] = dpp_add<0x124>(acc[r]);  // ror4
            acc[r] = dpp_add<0x128>(acc[r]);  // ror8 -> all 16 lanes have totals
        }

        // every lane picks its row total (select bits work for c3>=8 too)
        float s01 = (c3 & 1) ? acc[1] : acc[0];
        float s23 = (c3 & 1) ? acc[3] : acc[2];
        float s45 = (c3 & 1) ? acc[5] : acc[4];
        float s67 = (c3 & 1) ? acc[7] : acc[6];
        float sA  = (c3 & 2) ? s23 : s01;
        float sB  = (c3 & 2) ? s67 : s45;
        float dot = (c3 & 4) ? sB : sA;
        float hn  = tanh_fast(fmaf(xt, wih, bias) + dot);

        if (c3 < 8) s_h[p ^ 1][hwword] = hn;

        // symmetric per-wave y partial (no straggler): rows this wave owns
        float pv = (c3 < 8) ? hn * wo_my : 0.0f;
        pv = dpp_add<0xB1>(pv);
        pv = dpp_add<0x4E>(pv);
        pv = dpp_add<0x124>(pv);
        pv = dpp_add<0x128>(pv);
        pv += __shfl_xor(pv, 16);
        pv += __shfl_xor(pv, 32);
        if (lane == 0) s_part[step & 1][wv] = pv;

        __syncthreads();
        p ^= 1;
    }
}

extern "C" void kernel_launch(void* const* d_in, const int* in_sizes, int n_in,
                              void* d_out, int out_size, void* d_ws, size_t ws_size,
                              hipStream_t stream) {
    const float* x     = (const float*)d_in[0];
    const float* W_ih  = (const float*)d_in[1];
    const float* W_hh  = (const float*)d_in[2];
    const float* b_ih  = (const float*)d_in[3];
    const float* b_hh  = (const float*)d_in[4];
    const float* W_out = (const float*)d_in[5];
    const float* b_out = (const float*)d_in[6];
    float* y = (float*)d_out;

    hipLaunchKernelGGL(rnn_persist, dim3(NB), dim3(NTHR), 0, stream,
                       x, W_ih, W_hh, b_ih, b_hh, W_out, b_out, y);
}